// Round 11
// baseline (2548.854 us; speedup 1.0000x reference)
//
#include <hip/hip_runtime.h>

#define NTOK 8192     // B*S
#define DDIM 1024
#define FDIM 4096
#define NEXP 8
#define TDIM 64
#define MAXBLK 72     // max sum_e ceil(cnt_e/256) = 64+8

// ws layout (16KB granules everywhere):
#define HG_OFF   1048576u
#define W1B_OFF  (HG_OFF + 150994944u)     // Hg: 72*2*64 x 16KB = 144 MiB
#define W2B_OFF  (W1B_OFF + 67108864u)     // W1b: 8*16*32 x 16KB = 64 MiB
#define XGT_OFF  (W2B_OFF + 67108864u)     // W2b: 8*4*128 x 16KB = 64 MiB
#define WS_NEED  (XGT_OFF + 37748736u)     // XgT: 72*32 x 16KB = 36 MiB (total 324MB, verified fits)

typedef __bf16 bf16x8 __attribute__((ext_vector_type(8)));
typedef unsigned short u16x8 __attribute__((ext_vector_type(8)));
typedef unsigned short u16x4 __attribute__((ext_vector_type(4)));
typedef float f32x4 __attribute__((ext_vector_type(4)));

__device__ __forceinline__ float gelu_tanh(float h) {
  float u = 0.7978845608028654f * (h + 0.044715f * h * h * h);
  float e = __expf(2.0f * u);
  return 0.5f * h * (2.0f - 2.0f / (e + 1.0f));
}

__device__ __forceinline__ void glds16(const void* g, void* l) {
  __builtin_amdgcn_global_load_lds((const __attribute__((address_space(1))) void*)g,
                                   (__attribute__((address_space(3))) void*)l, 16, 0, 0);
}

#define VM0() asm volatile("s_waitcnt vmcnt(0)" ::: "memory")
#define SBAR() __syncthreads()

// ---------------- gating ----------------
__global__ __launch_bounds__(256) void gate_kernel(
    const float* __restrict__ x, const float* __restrict__ task,
    const float* __restrict__ alpha_p,
    const float* __restrict__ Wg_in, const float* __restrict__ bg_in,
    const float* __restrict__ Wg_task, const float* __restrict__ bg_task,
    int* __restrict__ cnt, float* __restrict__ wsum,
    int* __restrict__ tok_list, float* __restrict__ wt_list)
{
  __shared__ float s_wsum[NEXP];
  int tid = threadIdx.x;
  if (tid < NEXP) s_wsum[tid] = 0.0f;
  __syncthreads();

  int lane = tid & 63;
  int wid  = tid >> 6;
  int tok  = blockIdx.x * 4 + wid;
  float a  = alpha_p[0];

  const float* xr = x + (size_t)tok * DDIM;
  float accd[8] = {0,0,0,0,0,0,0,0};
#pragma unroll
  for (int i = 0; i < DDIM/64; ++i) {
    int d = lane + 64*i;
    float xv = xr[d];
    f32x4 wa = *(const f32x4*)(Wg_in + (size_t)d*8);
    f32x4 wb = *(const f32x4*)(Wg_in + (size_t)d*8 + 4);
#pragma unroll
    for (int j = 0; j < 4; ++j) {
      accd[j]   = fmaf(xv, wa[j], accd[j]);
      accd[4+j] = fmaf(xv, wb[j], accd[4+j]);
    }
  }
  float part[8];
  {
    int d = lane;
    float tv = task[(size_t)tok*TDIM + d];
    f32x4 wa = *(const f32x4*)(Wg_task + (size_t)d*8);
    f32x4 wb = *(const f32x4*)(Wg_task + (size_t)d*8 + 4);
#pragma unroll
    for (int j = 0; j < 4; ++j) {
      part[j]   = (1.0f-a)*accd[j]   + a*(tv*wa[j]);
      part[4+j] = (1.0f-a)*accd[4+j] + a*(tv*wb[j]);
    }
  }
#pragma unroll
  for (int e = 0; e < 8; ++e) {
#pragma unroll
    for (int m = 1; m < 64; m <<= 1) part[e] += __shfl_xor(part[e], m);
  }

  if (lane == 0) {
    float lg[8];
#pragma unroll
    for (int e = 0; e < 8; ++e) lg[e] = part[e] + (1.0f-a)*bg_in[e] + a*bg_task[e];
    int e0 = 0;
#pragma unroll
    for (int e = 1; e < 8; ++e) if (lg[e] > lg[e0]) e0 = e;
    int e1 = (e0 == 0) ? 1 : 0;
#pragma unroll
    for (int e = 0; e < 8; ++e) if (e != e0 && lg[e] > lg[e1]) e1 = e;
    float mx = lg[0];
#pragma unroll
    for (int e = 1; e < 8; ++e) mx = fmaxf(mx, lg[e]);
    float p[8], s = 0.0f;
#pragma unroll
    for (int e = 0; e < 8; ++e) { p[e] = __expf(lg[e] - mx); s += p[e]; }
    float inv = 1.0f / s;
#pragma unroll
    for (int e = 0; e < 8; ++e) atomicAdd(&s_wsum[e], p[e] * inv);
    float p1 = __expf(lg[e1] - lg[e0]);
    float w0 = 1.0f / (1.0f + p1);
    float w1 = p1 * w0;
    int pos0 = atomicAdd(&cnt[e0], 1);
    tok_list[e0*NTOK + pos0] = tok; wt_list[e0*NTOK + pos0] = w0;
    int pos1 = atomicAdd(&cnt[e1], 1);
    tok_list[e1*NTOK + pos1] = tok; wt_list[e1*NTOK + pos1] = w1;
  }
  __syncthreads();
  if (tid < NEXP) atomicAdd(&wsum[tid], s_wsum[tid]);
}

// ---------------- finalize ----------------
__global__ void finalize_kernel(const int* __restrict__ cnt, const float* __restrict__ wsum,
                                int* __restrict__ offs, float* __restrict__ laux,
                                int* __restrict__ blk_e, int* __restrict__ blk_m)
{
  if (threadIdx.x == 0) {
    int o = 0; float l = 0.0f; int nb = 0;
    for (int e = 0; e < NEXP; ++e) {
      offs[e] = o;
      for (int m0 = 0; m0 < cnt[e]; m0 += 256) {
        if (nb < MAXBLK) { blk_e[nb] = e; blk_m[nb] = m0; ++nb; }
      }
      l += (wsum[e] * (1.0f/NTOK)) * ((float)cnt[e] * (1.0f/NTOK));
      o += cnt[e];
    }
    for (; nb < MAXBLK; ++nb) blk_e[nb] = -1;
    *laux = l;
  }
}

// ---- prep: W -> bf16 16KB granules (256n x 32k, paired-row chunk format) ----
// Granule kt: 1024 chunks. Chunk cl: R=cl>>3, d=(cl&7)^(R&7), n=(R<<1)|(d>>2),
// kloc=(d&3)*8+j. Stored value = W[src_k][n]; src_k = kt*32+kloc (no perm) or
// perm within each 64-group: v=(kt&1)*32+kloc, src=((v&3)<<4)|(v>>2) (PERM).
template<bool PERM>
__global__ __launch_bounds__(256) void prep_w(const float* __restrict__ W,
                                              unsigned short* __restrict__ Wb,
                                              int N, int NKB, int NJ)
{
  int kb = blockIdx.x, J = blockIdx.y, e = blockIdx.z;
  int K = NKB*64;
  __shared__ unsigned short t[64*264];
  int tid = threadIdx.x;
  const float* src = W + ((size_t)e*K + (size_t)kb*64) * N + J*256;
  int k = tid >> 2, cg = tid & 3;
#pragma unroll
  for (int ii = 0; ii < 16; ++ii) {
    int n = cg*64 + ii*4;
    f32x4 v = *(const f32x4*)(src + (size_t)k*N + n);
    u16x4 b;
#pragma unroll
    for (int j = 0; j < 4; ++j) b[j] = __builtin_bit_cast(unsigned short, (__bf16)v[j]);
    *(u16x4*)&t[k*264 + n] = b;
  }
  __syncthreads();
  unsigned short* dst = Wb + ((size_t)(e*NJ + J)*NKB + kb) * 16384;  // 2 granules
#pragma unroll
  for (int i = 0; i < 8; ++i) {
    int c2 = i*256 + tid;            // [0,2048)
    int h  = c2 >> 10, cl = c2 & 1023;
    int R  = cl >> 3, dp = cl & 7;
    int d  = dp ^ (R & 7);
    int n  = (R << 1) | (d >> 2);
    int kb8 = (d & 3) * 8;
    u16x8 v;
#pragma unroll
    for (int j = 0; j < 8; ++j) {
      int vv = h*32 + kb8 + j;
      int sk = PERM ? (((vv & 3) << 4) | (vv >> 2)) : vv;
      v[j] = t[sk*264 + n];
    }
    *(u16x8*)(dst + (size_t)c2*8) = v;
  }
}

// ---- prep: gather X rows into 16KB granules (bi, kt), same chunk format ----
__global__ __launch_bounds__(256) void prep_gather_t(
    const float* __restrict__ X,
    const int* __restrict__ cnt, const int* __restrict__ tok_list,
    const int* __restrict__ blk_e, const int* __restrict__ blk_m,
    unsigned short* __restrict__ XgT)
{
  int kt = blockIdx.x, bi = blockIdx.y;
  int e = blk_e[bi];
  if (e < 0) return;
  int m0 = blk_m[bi], ce = cnt[e];
  __shared__ int s_tok[256];
  int tid = threadIdx.x;
  if (tid < 256) {
    int idx = m0 + tid;
    s_tok[tid] = tok_list[e*NTOK + ((idx < ce) ? idx : (ce-1))];
  }
  __syncthreads();
  unsigned short* dst = XgT + ((size_t)bi*32 + kt) * 8192;
#pragma unroll
  for (int i = 0; i < 4; ++i) {
    int c = i*256 + tid;             // [0,1024)
    int R = c >> 3, dp = c & 7;
    int d = dp ^ (R & 7);
    int row = (R << 1) | (d >> 2);
    int kloc = (d & 3) * 8;
    const float* src = X + (size_t)s_tok[row]*DDIM + kt*32 + kloc;
    f32x4 a = *(const f32x4*)(src);
    f32x4 b = *(const f32x4*)(src + 4);
    u16x8 v;
#pragma unroll
    for (int j = 0; j < 4; ++j) {
      v[j]   = __builtin_bit_cast(unsigned short, (__bf16)a[j]);
      v[4+j] = __builtin_bit_cast(unsigned short, (__bf16)b[j]);
    }
    *(u16x8*)(dst + (size_t)c*8) = v;
  }
}

// ===== 256x256 GEMMs, BK=32, 64KB LDS -> 2 blocks/CU (v11) =====
// 8 waves (2M x 4N), per-wave C=128x64 (acc[8][4]), 32 MFMA / K-step / wave.
// 2-phase: STAGE(next) -> COMPUTE(cur) -> vmcnt(0) -> barrier. Cross-block overlap
// (2 independent blocks/CU) hides the drain; XCD-local B panels via grid order.

#define STAGE(sa, sb, kt) do {                                                 \
  glds16(abase + (size_t)(kt)*16384 + t16,        (char*)(sa) + t16);          \
  glds16(abase + (size_t)(kt)*16384 + 8192 + t16, (char*)(sa) + 8192 + t16);   \
  glds16(bbase + (size_t)(kt)*16384 + t16,        (char*)(sb) + t16);          \
  glds16(bbase + (size_t)(kt)*16384 + 8192 + t16, (char*)(sb) + 8192 + t16);   \
} while (0)

#define COMPUTE(sa, sb) do {                                                   \
  bf16x8 bfv_[4];                                                              \
  _Pragma("unroll")                                                            \
  for (int ni_ = 0; ni_ < 4; ++ni_)                                            \
    bfv_[ni_] = *(const bf16x8*)&(sb)[boff0 + ni_*512];                        \
  _Pragma("unroll")                                                            \
  for (int mi_ = 0; mi_ < 8; ++mi_) {                                          \
    bf16x8 af_ = *(const bf16x8*)&(sa)[aoff0 + mi_*512];                       \
    _Pragma("unroll")                                                          \
    for (int ni_ = 0; ni_ < 4; ++ni_)                                          \
      acc[mi_][ni_] = __builtin_amdgcn_mfma_f32_16x16x32_bf16(                 \
          af_, bfv_[ni_], acc[mi_][ni_], 0, 0, 0);                             \
  }                                                                            \
} while (0)

#define KLOOP(NT) do {                                                         \
  STAGE(sA0, sB0, 0);                                                          \
  VM0(); SBAR();                                                               \
  for (int kt = 0; kt < (NT); kt += 2) {                                       \
    STAGE(sA1, sB1, kt+1);                                                     \
    COMPUTE(sA0, sB0);                                                         \
    VM0(); SBAR();                                                             \
    if (kt + 2 < (NT)) STAGE(sA0, sB0, kt+2);                                  \
    COMPUTE(sA1, sB1);                                                         \
    VM0(); SBAR();                                                             \
  }                                                                            \
} while (0)

// ---------------- GEMM1: Hg = gelu(XgT @ W1b + b1) ----------------
// grid (J=16, bi) -> XCD = J%8: each XCD keeps 2 W1 panels hot in L2.
__global__ __launch_bounds__(512, 4) void gemm1_v11(
    const unsigned short* __restrict__ XgT, const unsigned short* __restrict__ W1b,
    const float* __restrict__ b1,
    const int* __restrict__ cnt,
    const int* __restrict__ blk_e, const int* __restrict__ blk_m,
    unsigned short* __restrict__ Hg)
{
  int J = blockIdx.x;
  int bi = blockIdx.y;
  int e = blk_e[bi];
  if (e < 0) return;
  int m0 = blk_m[bi];
  int ce = cnt[e];

  __shared__ __align__(16) unsigned short sA0[8192], sB0[8192], sA1[8192], sB1[8192];

  int tid = threadIdx.x;
  int w = tid >> 6, l = tid & 63;
  int wr = w >> 2, wc = w & 3;
  int q = l & 15, g = l >> 4;
  const int t16 = tid * 16;

  const char* abase = (const char*)XgT + (size_t)bi * 524288;
  const char* bbase = (const char*)W1b + (size_t)(e*16 + J) * 32 * 16384;

  int hq = q >> 1;
  int swz = ((((q & 1) << 2) | g) ^ (hq & 7));
  const int aoff0 = (wr*64 + hq)*64 + swz*8;
  const int boff0 = (wc*32 + hq)*64 + swz*8;

  f32x4 acc[8][4];
#pragma unroll
  for (int mi = 0; mi < 8; ++mi)
#pragma unroll
    for (int ni = 0; ni < 4; ++ni) acc[mi][ni] = (f32x4){0.f,0.f,0.f,0.f};

  KLOOP(DDIM/32);

  // epilogue: bias+gelu -> Hg 16KB granules. Logical pos v=q*4+ni (phys col ni*16+q).
  int G = J*4 + wc;                       // 64-col group of H, [0,64)
  int kt2g = G*2 + (q >> 3);              // [0,128)
  unsigned short* hgb = Hg + ((size_t)(bi*2 + (kt2g >> 6))*64 + (kt2g & 63)) * 8192;
  int vh = (q & 7) >> 1;                  // vloc>>3
  int n0 = J*256;
  float bias[4];
#pragma unroll
  for (int ni = 0; ni < 4; ++ni) bias[ni] = b1[(size_t)e*FDIM + n0 + wc*64 + ni*16 + q];
#pragma unroll
  for (int mi = 0; mi < 8; ++mi) {
#pragma unroll
    for (int j = 0; j < 4; ++j) {
      int r = wr*128 + mi*16 + g*4 + j;
      if (m0 + r >= ce) continue;
      u16x4 hv;
#pragma unroll
      for (int ni = 0; ni < 4; ++ni) {
        float h = acc[mi][ni][j] + bias[ni];
        hv[ni] = __builtin_bit_cast(unsigned short, (__bf16)gelu_tanh(h));
      }
      int R = r >> 1;
      int d = ((r & 1) << 2) | vh;
      int cl = R*8 + (d ^ (R & 7));
      *(u16x4*)&hgb[cl*8 + (q & 1)*4] = hv;
    }
  }
}

// ---------------- GEMM2: out += w * (Hg @ W2b + b2) ----------------
// grid (Js=8, bi): Js = J + 4*s -> XCD = Js: one W2 panel per XCD in L2.
__global__ __launch_bounds__(512, 4) void gemm2_v11(
    const unsigned short* __restrict__ Hg, const unsigned short* __restrict__ W2b,
    const float* __restrict__ b2,
    const int* __restrict__ cnt, const int* __restrict__ offs,
    const int* __restrict__ tok_list, const float* __restrict__ wt_list,
    const int* __restrict__ blk_e, const int* __restrict__ blk_m,
    float* __restrict__ out)
{
  int Js = blockIdx.x;
  int J = Js & 3, s = Js >> 2;
  int bi = blockIdx.y;
  int e = blk_e[bi];
  if (e < 0) return;
  int m0 = blk_m[bi];
  int ce = cnt[e];
  int off = offs[e];

  __shared__ __align__(16) unsigned short sA0[8192], sB0[8192], sA1[8192], sB1[8192];
  __shared__ int   s_tok[256];
  __shared__ float s_wt[256];

  int tid = threadIdx.x;
  if (tid < 256) {
    int idx = m0 + tid;
    int cidx = (idx < ce) ? idx : (ce-1);
    s_tok[tid] = tok_list[e*NTOK + cidx];
    s_wt[tid]  = (idx < ce) ? wt_list[e*NTOK + cidx] : 0.0f;
  }
  __syncthreads();

  int w = tid >> 6, l = tid & 63;
  int wr = w >> 2, wc = w & 3;
  int q = l & 15, g = l >> 4;
  const int t16 = tid * 16;

  const char* abase = (const char*)Hg + ((size_t)(bi*2 + s) << 20);
  const char* bbase = (const char*)W2b + (size_t)((e*4 + J)*128 + s*64) * 16384;

  int hq = q >> 1;
  int swz = ((((q & 1) << 2) | g) ^ (hq & 7));
  const int aoff0 = (wr*64 + hq)*64 + swz*8;
  const int boff0 = (wc*32 + hq)*64 + swz*8;

  f32x4 acc[8][4];
#pragma unroll
  for (int mi = 0; mi < 8; ++mi)
#pragma unroll
    for (int ni = 0; ni < 4; ++ni) acc[mi][ni] = (f32x4){0.f,0.f,0.f,0.f};

  KLOOP(FDIM/32/2);

  int n0 = J*256;
  float bias[4];
#pragma unroll
  for (int ni = 0; ni < 4; ++ni)
    bias[ni] = (s == 0) ? b2[(size_t)e*DDIM + n0 + wc*64 + ni*16 + q] : 0.0f;
#pragma unroll
  for (int mi = 0; mi < 8; ++mi) {
#pragma unroll
    for (int j = 0; j < 4; ++j) {
      int r = wr*128 + mi*16 + g*4 + j;
      if (m0 + r >= ce) continue;
      int tok = s_tok[r];
      float wt = s_wt[r];
      float* orow = out + (size_t)tok * DDIM;
#pragma unroll
      for (int ni = 0; ni < 4; ++ni) {
        float y = acc[mi][ni][j] + bias[ni];
        unsafeAtomicAdd(&orow[n0 + wc*64 + ni*16 + q], wt * y);
      }
    }
  }
}

// ---------------- launch ----------------
extern "C" void kernel_launch(void* const* d_in, const int* in_sizes, int n_in,
                              void* d_out, int out_size, void* d_ws, size_t ws_size,
                              hipStream_t stream)
{
  const float* x       = (const float*)d_in[0];
  const float* task    = (const float*)d_in[1];
  const float* alpha   = (const float*)d_in[2];
  const float* Wg_in   = (const float*)d_in[3];
  const float* bg_in   = (const float*)d_in[4];
  const float* Wg_task = (const float*)d_in[5];
  const float* bg_task = (const float*)d_in[6];
  const float* W1      = (const float*)d_in[7];
  const float* b1      = (const float*)d_in[8];
  const float* W2      = (const float*)d_in[9];
  const float* b2      = (const float*)d_in[10];
  float* out = (float*)d_out;

  char* ws = (char*)d_ws;
  int*   cnt      = (int*)(ws + 0);
  float* wsum     = (float*)(ws + 32);
  int*   offs     = (int*)(ws + 64);
  int*   blk_e    = (int*)(ws + 128);
  int*   blk_m    = (int*)(ws + 512);
  int*   tok_list = (int*)(ws + 4096);
  float* wt_list  = (float*)(ws + 4096 + NTOK*NEXP*4);
  unsigned short* Hg  = (unsigned short*)(ws + HG_OFF);
  unsigned short* W1b = (unsigned short*)(ws + W1B_OFF);
  unsigned short* W2b = (unsigned short*)(ws + W2B_OFF);
  unsigned short* XgT = (unsigned short*)(ws + XGT_OFF);

  hipMemsetAsync(d_out, 0, (size_t)out_size * sizeof(float), stream);
  hipMemsetAsync(ws, 0, 128, stream);
  gate_kernel<<<NTOK/4, 256, 0, stream>>>(x, task, alpha, Wg_in, bg_in, Wg_task, bg_task,
                                          cnt, wsum, tok_list, wt_list);
  finalize_kernel<<<1, 64, 0, stream>>>(cnt, wsum, offs, out + (size_t)NTOK*DDIM, blk_e, blk_m);

  prep_w<false><<<dim3(16, 16, NEXP), 256, 0, stream>>>(W1, W1b, FDIM, 16, 16);
  prep_w<true ><<<dim3(64,  4, NEXP), 256, 0, stream>>>(W2, W2b, DDIM, 64, 4);
  prep_gather_t<<<dim3(32, MAXBLK), 256, 0, stream>>>(x, cnt, tok_list, blk_e, blk_m, XgT);

  gemm1_v11<<<dim3(16, MAXBLK), 512, 0, stream>>>(XgT, W1b, b1, cnt, blk_e, blk_m, Hg);
  gemm2_v11<<<dim3(8, MAXBLK), 512, 0, stream>>>(Hg, W2b, b2, cnt, offs, tok_list, wt_list,
                                                 blk_e, blk_m, out);
}

// Round 12
// 823.522 us; speedup vs baseline: 3.0951x; 3.0951x over previous
//
#include <hip/hip_runtime.h>

#define NTOK 8192     // B*S
#define DDIM 1024
#define FDIM 4096
#define NEXP 8
#define TDIM 64
#define MAXBLK 72     // max sum_e ceil(cnt_e/256) = 64+8

// ws layout:
#define H_OFF   (1u<<20)
#define W1B_OFF (H_OFF + 134217728u)      // H: 16384 x 4096 bf16 = 128 MiB
#define W2B_OFF (W1B_OFF + 67108864u)     // W1b: 64 MiB
#define XB_OFF  (W2B_OFF + 67108864u)     // W2b: 64 MiB
#define FULL_WS (XB_OFF + 16777216u)      // Xb: 16 MiB

typedef __bf16 bf16x8 __attribute__((ext_vector_type(8)));
typedef unsigned short u16x8 __attribute__((ext_vector_type(8)));
typedef unsigned short u16x4 __attribute__((ext_vector_type(4)));
typedef float f32x4 __attribute__((ext_vector_type(4)));

__device__ __forceinline__ float gelu_tanh(float h) {
  float u = 0.7978845608028654f * (h + 0.044715f * h * h * h);
  float e = __expf(2.0f * u);
  return 0.5f * h * (2.0f - 2.0f / (e + 1.0f));
}

__device__ __forceinline__ void glds16(const void* g, void* l) {
  __builtin_amdgcn_global_load_lds((const __attribute__((address_space(1))) void*)g,
                                   (__attribute__((address_space(3))) void*)l, 16, 0, 0);
}

// ---------------- gating ----------------
__global__ __launch_bounds__(256) void gate_kernel(
    const float* __restrict__ x, const float* __restrict__ task,
    const float* __restrict__ alpha_p,
    const float* __restrict__ Wg_in, const float* __restrict__ bg_in,
    const float* __restrict__ Wg_task, const float* __restrict__ bg_task,
    int* __restrict__ cnt, float* __restrict__ wsum,
    int* __restrict__ tok_list, float* __restrict__ wt_list)
{
  __shared__ float s_wsum[NEXP];
  int tid = threadIdx.x;
  if (tid < NEXP) s_wsum[tid] = 0.0f;
  __syncthreads();

  int lane = tid & 63;
  int wid  = tid >> 6;
  int tok  = blockIdx.x * 4 + wid;
  float a  = alpha_p[0];

  const float* xr = x + (size_t)tok * DDIM;
  float accd[8] = {0,0,0,0,0,0,0,0};
#pragma unroll
  for (int i = 0; i < DDIM/64; ++i) {
    int d = lane + 64*i;
    float xv = xr[d];
    f32x4 wa = *(const f32x4*)(Wg_in + (size_t)d*8);
    f32x4 wb = *(const f32x4*)(Wg_in + (size_t)d*8 + 4);
#pragma unroll
    for (int j = 0; j < 4; ++j) {
      accd[j]   = fmaf(xv, wa[j], accd[j]);
      accd[4+j] = fmaf(xv, wb[j], accd[4+j]);
    }
  }
  float part[8];
  {
    int d = lane;
    float tv = task[(size_t)tok*TDIM + d];
    f32x4 wa = *(const f32x4*)(Wg_task + (size_t)d*8);
    f32x4 wb = *(const f32x4*)(Wg_task + (size_t)d*8 + 4);
#pragma unroll
    for (int j = 0; j < 4; ++j) {
      part[j]   = (1.0f-a)*accd[j]   + a*(tv*wa[j]);
      part[4+j] = (1.0f-a)*accd[4+j] + a*(tv*wb[j]);
    }
  }
#pragma unroll
  for (int e = 0; e < 8; ++e) {
#pragma unroll
    for (int m = 1; m < 64; m <<= 1) part[e] += __shfl_xor(part[e], m);
  }

  if (lane == 0) {
    float lg[8];
#pragma unroll
    for (int e = 0; e < 8; ++e) lg[e] = part[e] + (1.0f-a)*bg_in[e] + a*bg_task[e];
    int e0 = 0;
#pragma unroll
    for (int e = 1; e < 8; ++e) if (lg[e] > lg[e0]) e0 = e;
    int e1 = (e0 == 0) ? 1 : 0;
#pragma unroll
    for (int e = 0; e < 8; ++e) if (e != e0 && lg[e] > lg[e1]) e1 = e;
    float mx = lg[0];
#pragma unroll
    for (int e = 1; e < 8; ++e) mx = fmaxf(mx, lg[e]);
    float p[8], s = 0.0f;
#pragma unroll
    for (int e = 0; e < 8; ++e) { p[e] = __expf(lg[e] - mx); s += p[e]; }
    float inv = 1.0f / s;
#pragma unroll
    for (int e = 0; e < 8; ++e) atomicAdd(&s_wsum[e], p[e] * inv);
    float p1 = __expf(lg[e1] - lg[e0]);
    float w0 = 1.0f / (1.0f + p1);
    float w1 = p1 * w0;
    int pos0 = atomicAdd(&cnt[e0], 1);
    tok_list[e0*NTOK + pos0] = tok; wt_list[e0*NTOK + pos0] = w0;
    int pos1 = atomicAdd(&cnt[e1], 1);
    tok_list[e1*NTOK + pos1] = tok; wt_list[e1*NTOK + pos1] = w1;
  }
  __syncthreads();
  if (tid < NEXP) atomicAdd(&wsum[tid], s_wsum[tid]);
}

// ---------------- finalize: offsets + l_aux + block table ----------------
__global__ void finalize_kernel(const int* __restrict__ cnt, const float* __restrict__ wsum,
                                int* __restrict__ offs, float* __restrict__ laux,
                                int* __restrict__ blk_e, int* __restrict__ blk_m)
{
  if (threadIdx.x == 0) {
    int o = 0; float l = 0.0f; int nb = 0;
    for (int e = 0; e < NEXP; ++e) {
      offs[e] = o;
      for (int m0 = 0; m0 < cnt[e]; m0 += 256) {
        if (nb < MAXBLK) { blk_e[nb] = e; blk_m[nb] = m0; ++nb; }
      }
      l += (wsum[e] * (1.0f/NTOK)) * ((float)cnt[e] * (1.0f/NTOK));
      o += cnt[e];
    }
    for (; nb < MAXBLK; ++nb) blk_e[nb] = -1;
    *laux = l;
  }
}

// ---------------- prep: X -> bf16 ----------------
__global__ __launch_bounds__(256) void prep_x(const float* __restrict__ X,
                                              unsigned short* __restrict__ Xb)
{
  size_t i = ((size_t)blockIdx.x*256 + threadIdx.x)*8;
  f32x4 a = *(const f32x4*)(X + i);
  f32x4 b = *(const f32x4*)(X + i + 4);
  u16x8 v;
#pragma unroll
  for (int j = 0; j < 4; ++j) {
    v[j]   = __builtin_bit_cast(unsigned short, (__bf16)a[j]);
    v[4+j] = __builtin_bit_cast(unsigned short, (__bf16)b[j]);
  }
  *(u16x8*)(Xb + i) = v;
}

// ---------------- prep: W -> bf16, [n][k] tiles 256x64, swizzled ----------------
// Tile (e,J,kb): 32KB; chunk c=(r<<3)|cc at byte c*16 holds
// W[kb*64 + perm((cc^(r&7))*8+j)][J*256+r], j=0..7.
// PERM (W2): source k within each 64-group = ((p&3)<<4)|(p>>2)  (H col order).
template<bool PERM>
__global__ __launch_bounds__(256) void prep_w(const float* __restrict__ W,
                                              unsigned short* __restrict__ Wb,
                                              int N, int NKB, int NJ)
{
  int kb = blockIdx.x, J = blockIdx.y, e = blockIdx.z;
  int K = NKB*64;
  __shared__ unsigned short t[64*264];
  int tid = threadIdx.x;
  const float* src = W + ((size_t)e*K + (size_t)kb*64) * N + J*256;
  int k = tid >> 2, cg = tid & 3;
#pragma unroll
  for (int ii = 0; ii < 16; ++ii) {
    int n = cg*64 + ii*4;
    f32x4 v = *(const f32x4*)(src + (size_t)k*N + n);
    u16x4 b;
#pragma unroll
    for (int j = 0; j < 4; ++j) b[j] = __builtin_bit_cast(unsigned short, (__bf16)v[j]);
    *(u16x4*)&t[k*264 + n] = b;
  }
  __syncthreads();
  unsigned short* dst = Wb + ((size_t)(e*NJ + J)*NKB + kb)*16384;
#pragma unroll
  for (int i = 0; i < 8; ++i) {
    int c = i*256 + tid;
    int r = c >> 3, cc = c & 7;
    u16x8 v;
#pragma unroll
    for (int j = 0; j < 8; ++j) {
      int v64 = (cc ^ (r&7))*8 + j;
      int kl  = PERM ? (((v64 & 3) << 4) | (v64 >> 2)) : v64;
      v[j] = t[kl*264 + r];
    }
    *(u16x8*)(dst + c*8) = v;
  }
}

// ======================= 256x256 2-phase double-buffered GEMMs ==================
// 8 waves (2M x 4N), BK=64, per-wave C=128x64 (acc[8][4]).
// STAGE(next buf) -> COMPUTE(cur buf) -> vmcnt(0) -> s_barrier   (1 barrier/K-tile)

#define STAGE(sa, sb, ks) do {                                              \
  _Pragma("unroll")                                                         \
  for (int i_ = 0; i_ < 4; ++i_) {                                          \
    glds16(asrc[i_] + (size_t)(ks)*128, (char*)(sa) + dstoff[i_]);          \
    glds16(bsrc + (size_t)(ks)*32768 + i_*8192, (char*)(sb) + dstoff[i_]);  \
  }                                                                         \
} while (0)

#define COMPUTE(sa, sb) do {                                                \
  _Pragma("unroll")                                                         \
  for (int kk_ = 0; kk_ < 2; ++kk_) {                                       \
    int csw_ = ((kk_*4 + g) ^ (q & 7)) << 3;                                \
    bf16x8 bfv_[4];                                                         \
    _Pragma("unroll")                                                       \
    for (int ni_ = 0; ni_ < 4; ++ni_)                                       \
      bfv_[ni_] = *(const bf16x8*)&(sb)[(wc*64 + ni_*16 + q)*64 + csw_];    \
    _Pragma("unroll")                                                       \
    for (int mi_ = 0; mi_ < 8; ++mi_) {                                     \
      bf16x8 af_ = *(const bf16x8*)&(sa)[(wr*128 + mi_*16 + q)*64 + csw_];  \
      _Pragma("unroll")                                                     \
      for (int ni_ = 0; ni_ < 4; ++ni_)                                     \
        acc[mi_][ni_] = __builtin_amdgcn_mfma_f32_16x16x32_bf16(af_, bfv_[ni_], acc[mi_][ni_], 0, 0, 0); \
    }                                                                       \
  }                                                                         \
} while (0)

// ---------------- GEMM1: H = gelu(gather(Xb) @ W1b + b1) ----------------
__global__ __launch_bounds__(512) void gemm1_v4(
    const unsigned short* __restrict__ Xb, const unsigned short* __restrict__ W1b,
    const float* __restrict__ b1,
    const int* __restrict__ cnt, const int* __restrict__ offs,
    const int* __restrict__ tok_list,
    const int* __restrict__ blk_e, const int* __restrict__ blk_m,
    unsigned short* __restrict__ H)
{
  int e = blk_e[blockIdx.x];
  if (e < 0) return;
  int m0 = blk_m[blockIdx.x];
  int ce = cnt[e];
  int off = offs[e];
  int J = blockIdx.y;

  __shared__ __align__(16) unsigned short sA0[256*64], sB0[256*64];
  __shared__ __align__(16) unsigned short sA1[256*64], sB1[256*64];
  __shared__ int s_tok[256];

  int tid = threadIdx.x;
  if (tid < 256) {
    int idx = m0 + tid;
    s_tok[tid] = tok_list[e*NTOK + ((idx < ce) ? idx : (ce-1))];
  }
  __syncthreads();

  int w = tid >> 6, l = tid & 63;
  int wr = w >> 2, wc = w & 3;
  int q = l & 15, g = l >> 4;

  const char* asrc[4];
  int dstoff[4];
#pragma unroll
  for (int i = 0; i < 4; ++i) {
    int c = i*512 + tid;
    int r = c >> 3, cc = c & 7;
    asrc[i]  = (const char*)(Xb + (size_t)s_tok[r]*DDIM) + ((cc ^ (r&7)) << 4);
    dstoff[i] = c*16;
  }
  const char* bsrc = (const char*)W1b + ((size_t)(e*16 + J)*16)*32768 + (size_t)tid*16;

  f32x4 acc[8][4];
#pragma unroll
  for (int mi = 0; mi < 8; ++mi)
#pragma unroll
    for (int ni = 0; ni < 4; ++ni) acc[mi][ni] = (f32x4){0.f,0.f,0.f,0.f};

  STAGE(sA0, sB0, 0);
  asm volatile("s_waitcnt vmcnt(0)" ::: "memory");
  __builtin_amdgcn_s_barrier();

#define NK1 (DDIM/64)
  for (int ks = 0; ks < NK1; ks += 2) {
    STAGE(sA1, sB1, ks+1);
    COMPUTE(sA0, sB0);
    asm volatile("s_waitcnt vmcnt(0)" ::: "memory");
    __builtin_amdgcn_s_barrier();
    if (ks + 2 < NK1) STAGE(sA0, sB0, ks+2);
    COMPUTE(sA1, sB1);
    asm volatile("s_waitcnt vmcnt(0)" ::: "memory");
    __builtin_amdgcn_s_barrier();
  }

  // epilogue: bias+gelu, permuted H col order (phys = base + q*4 + ni)
  int n0 = J*256;
  float bias[4];
#pragma unroll
  for (int ni = 0; ni < 4; ++ni) bias[ni] = b1[(size_t)e*FDIM + n0 + wc*64 + ni*16 + q];
#pragma unroll
  for (int mi = 0; mi < 8; ++mi) {
#pragma unroll
    for (int j = 0; j < 4; ++j) {
      int r = wr*128 + mi*16 + g*4 + j;
      if (m0 + r >= ce) continue;
      u16x4 hv;
#pragma unroll
      for (int ni = 0; ni < 4; ++ni) {
        float h = acc[mi][ni][j] + bias[ni];
        hv[ni] = __builtin_bit_cast(unsigned short, (__bf16)gelu_tanh(h));
      }
      *(u16x4*)&H[(size_t)(off + m0 + r)*FDIM + n0 + wc*64 + q*4] = hv;
    }
  }
}

// ---------------- GEMM2: out[tok] += w * (H @ W2b + b2) ----------------
__global__ __launch_bounds__(512) void gemm2_v4(
    const unsigned short* __restrict__ H, const unsigned short* __restrict__ W2b,
    const float* __restrict__ b2,
    const int* __restrict__ cnt, const int* __restrict__ offs,
    const int* __restrict__ tok_list, const float* __restrict__ wt_list,
    const int* __restrict__ blk_e, const int* __restrict__ blk_m,
    float* __restrict__ out)
{
  int e = blk_e[blockIdx.x];
  if (e < 0) return;
  int m0 = blk_m[blockIdx.x];
  int ce = cnt[e];
  int off = offs[e];
  int J = blockIdx.y;

  __shared__ __align__(16) unsigned short sA0[256*64], sB0[256*64];
  __shared__ __align__(16) unsigned short sA1[256*64], sB1[256*64];
  __shared__ int   s_tok[256];
  __shared__ float s_wt[256];

  int tid = threadIdx.x;
  if (tid < 256) {
    int idx = m0 + tid;
    int cidx = (idx < ce) ? idx : (ce-1);
    s_tok[tid] = tok_list[e*NTOK + cidx];
    s_wt[tid]  = (idx < ce) ? wt_list[e*NTOK + cidx] : 0.0f;
  }
  __syncthreads();

  int w = tid >> 6, l = tid & 63;
  int wr = w >> 2, wc = w & 3;
  int q = l & 15, g = l >> 4;

  const char* asrc[4];
  int dstoff[4];
#pragma unroll
  for (int i = 0; i < 4; ++i) {
    int c = i*512 + tid;
    int r = c >> 3, cc = c & 7;
    int rr = (m0 + r < ce) ? r : (ce-1-m0);
    asrc[i]  = (const char*)(H + (size_t)(off + m0 + rr)*FDIM) + ((cc ^ (r&7)) << 4);
    dstoff[i] = c*16;
  }
  const char* bsrc = (const char*)W2b + ((size_t)(e*4 + J)*64)*32768 + (size_t)tid*16;

  f32x4 acc[8][4];
#pragma unroll
  for (int mi = 0; mi < 8; ++mi)
#pragma unroll
    for (int ni = 0; ni < 4; ++ni) acc[mi][ni] = (f32x4){0.f,0.f,0.f,0.f};

  STAGE(sA0, sB0, 0);
  asm volatile("s_waitcnt vmcnt(0)" ::: "memory");
  __builtin_amdgcn_s_barrier();

#define NK2 (FDIM/64)
  for (int ks = 0; ks < NK2; ks += 2) {
    STAGE(sA1, sB1, ks+1);
    COMPUTE(sA0, sB0);
    asm volatile("s_waitcnt vmcnt(0)" ::: "memory");
    __builtin_amdgcn_s_barrier();
    if (ks + 2 < NK2) STAGE(sA0, sB0, ks+2);
    COMPUTE(sA1, sB1);
    asm volatile("s_waitcnt vmcnt(0)" ::: "memory");
    __builtin_amdgcn_s_barrier();
  }

  int n0 = J*256;
  float bias[4];
#pragma unroll
  for (int ni = 0; ni < 4; ++ni) bias[ni] = b2[(size_t)e*DDIM + n0 + wc*64 + ni*16 + q];
#pragma unroll
  for (int mi = 0; mi < 8; ++mi) {
#pragma unroll
    for (int j = 0; j < 4; ++j) {
      int r = wr*128 + mi*16 + g*4 + j;
      if (m0 + r >= ce) continue;
      int tok = s_tok[r];
      float wt = s_wt[r];
      float* orow = out + (size_t)tok * DDIM;
#pragma unroll
      for (int ni = 0; ni < 4; ++ni) {
        float y = acc[mi][ni][j] + bias[ni];
        unsafeAtomicAdd(&orow[n0 + wc*64 + ni*16 + q], wt * y);
      }
    }
  }
}

// ---------------- launch ----------------
extern "C" void kernel_launch(void* const* d_in, const int* in_sizes, int n_in,
                              void* d_out, int out_size, void* d_ws, size_t ws_size,
                              hipStream_t stream)
{
  const float* x       = (const float*)d_in[0];
  const float* task    = (const float*)d_in[1];
  const float* alpha   = (const float*)d_in[2];
  const float* Wg_in   = (const float*)d_in[3];
  const float* bg_in   = (const float*)d_in[4];
  const float* Wg_task = (const float*)d_in[5];
  const float* bg_task = (const float*)d_in[6];
  const float* W1      = (const float*)d_in[7];
  const float* b1      = (const float*)d_in[8];
  const float* W2      = (const float*)d_in[9];
  const float* b2      = (const float*)d_in[10];
  float* out = (float*)d_out;

  char* ws = (char*)d_ws;
  int*   cnt      = (int*)(ws + 0);
  float* wsum     = (float*)(ws + 32);
  int*   offs     = (int*)(ws + 64);
  int*   blk_e    = (int*)(ws + 128);
  int*   blk_m    = (int*)(ws + 512);
  int*   tok_list = (int*)(ws + 4096);
  float* wt_list  = (float*)(ws + 4096 + NTOK*NEXP*4);
  unsigned short* H   = (unsigned short*)(ws + H_OFF);
  unsigned short* W1b = (unsigned short*)(ws + W1B_OFF);
  unsigned short* W2b = (unsigned short*)(ws + W2B_OFF);
  unsigned short* Xb  = (unsigned short*)(ws + XB_OFF);

  hipMemsetAsync(d_out, 0, (size_t)out_size * sizeof(float), stream);
  hipMemsetAsync(ws, 0, 128, stream);
  gate_kernel<<<NTOK/4, 256, 0, stream>>>(x, task, alpha, Wg_in, bg_in, Wg_task, bg_task,
                                          cnt, wsum, tok_list, wt_list);
  finalize_kernel<<<1, 64, 0, stream>>>(cnt, wsum, offs, out + (size_t)NTOK*DDIM, blk_e, blk_m);
  prep_x<<<NTOK*DDIM/2048, 256, 0, stream>>>(x, Xb);
  prep_w<false><<<dim3(16, 16, NEXP), 256, 0, stream>>>(W1, W1b, FDIM, 16, 16);
  prep_w<true ><<<dim3(64,  4, NEXP), 256, 0, stream>>>(W2, W2b, DDIM, 64, 4);
  gemm1_v4<<<dim3(MAXBLK, FDIM/256), 512, 0, stream>>>(Xb, W1b, b1, cnt, offs, tok_list,
                                                       blk_e, blk_m, H);
  gemm2_v4<<<dim3(MAXBLK, DDIM/256), 512, 0, stream>>>(H, W2b, b2, cnt, offs, tok_list, wt_list,
                                                       blk_e, blk_m, out);
}